// Round 7
// baseline (193.138 us; speedup 1.0000x reference)
//
#include <hip/hip_runtime.h>
#include <math.h>

#define N 4096
#define IN_F 256
#define OUT_F 64
#define HEADS 4
#define NEG 0.2f
#define JSPLIT 8
#define JLEN (N / JSPLIT)        // 512
#define NC (JLEN / 32)           // 16 chunks
#define LOG2E 1.44269504088896f

typedef float f32x4 __attribute__((ext_vector_type(4)));
typedef short short8 __attribute__((ext_vector_type(8)));

#define FMA4S(A, s, V) do { (A).x = fmaf((s),(V).x,(A).x); (A).y = fmaf((s),(V).y,(A).y); \
                            (A).z = fmaf((s),(V).z,(A).z); (A).w = fmaf((s),(V).w,(A).w); } while(0)

__device__ __forceinline__ unsigned short f2bf(float x) {
  unsigned int u = __float_as_uint(x);
  u += 0x7fffu + ((u >> 16) & 1u);   // RNE
  return (unsigned short)(u >> 16);
}

__device__ __forceinline__ float exp2_fast(float x) {
#if __has_builtin(__builtin_amdgcn_exp2f)
  return __builtin_amdgcn_exp2f(x);
#else
  return exp2f(x);
#endif
}

// pack bf16(p1)<<16 | bf16(p0), round-half-up
__device__ __forceinline__ int pack_bf2(float p0, float p1) {
  unsigned u0 = __float_as_uint(p0) + 0x8000u;
  unsigned u1 = __float_as_uint(p1) + 0x8000u;
  return (int)__builtin_amdgcn_perm(u1, u0, 0x07060302u);
}

// ---------------------------------------------------------------------------
// Kernel 1: xt = x @ W[h], 64-row tile per block, grid (64,4), block 256.
// W[h] staged through LDS in 4 k-stages. 4x4 register tile per thread.
// Emits src/dst (log2e-scaled) + xtB (bf16 B-frag layout).
// ---------------------------------------------------------------------------
__global__ __launch_bounds__(256) void k_xt(const float* __restrict__ x,
                                            const float* __restrict__ W,
                                            const float* __restrict__ a,
                                            short* __restrict__ xtB,
                                            float* __restrict__ src,
                                            float* __restrict__ dst) {
  __shared__ __align__(16) float xls[64 * 68];  // x tile, stride 68 floats
  __shared__ __align__(16) float wls[64 * 64];  // W k-slice
  const int t  = threadIdx.x;
  const int h  = blockIdx.y;
  const int i0 = blockIdx.x * 64;
  const int fg = t & 15;
  const int rg = t >> 4;

  float4 acc[4];
  acc[0] = acc[1] = acc[2] = acc[3] = make_float4(0.f, 0.f, 0.f, 0.f);

  const float4* xg = (const float4*)x;
  const float4* wg = (const float4*)W;
  float4* xls4 = (float4*)xls;
  float4* wls4 = (float4*)wls;
  const float4* xr4 = (const float4*)xls;
  const float4* wr4 = (const float4*)wls;

  for (int kt = 0; kt < 4; ++kt) {
    __syncthreads();
    #pragma unroll
    for (int s = 0; s < 4; ++s) {
      int f4i = t + 256 * s;
      int row = f4i >> 4, c4 = f4i & 15;
      xls4[row * 17 + c4] = xg[(size_t)(i0 + row) * 64 + kt * 16 + c4];
    }
    #pragma unroll
    for (int s = 0; s < 4; ++s) {
      int f4i = t + 256 * s;
      int kk = f4i >> 4, c4 = f4i & 15;
      wls4[kk * 16 + c4] = wg[(size_t)(h * 256 + kt * 64 + kk) * 16 + c4];
    }
    __syncthreads();
    #pragma unroll 4
    for (int kk = 0; kk < 64; kk += 4) {
      float4 wv0 = wr4[(kk + 0) * 16 + fg];
      float4 wv1 = wr4[(kk + 1) * 16 + fg];
      float4 wv2 = wr4[(kk + 2) * 16 + fg];
      float4 wv3 = wr4[(kk + 3) * 16 + fg];
      #pragma unroll
      for (int q = 0; q < 4; ++q) {
        float4 xv = xr4[(rg * 4 + q) * 17 + (kk >> 2)];
        FMA4S(acc[q], xv.x, wv0);
        FMA4S(acc[q], xv.y, wv1);
        FMA4S(acc[q], xv.z, wv2);
        FMA4S(acc[q], xv.w, wv3);
      }
    }
  }

  const float4* a4 = (const float4*)a;
  float4 as = a4[h * 32 + fg];
  float4 ad = a4[h * 32 + 16 + fg];
  as.x *= LOG2E; as.y *= LOG2E; as.z *= LOG2E; as.w *= LOG2E;
  ad.x *= LOG2E; ad.y *= LOG2E; ad.z *= LOG2E; ad.w *= LOG2E;
  #pragma unroll
  for (int q = 0; q < 4; ++q) {
    float s_ = acc[q].x * as.x + acc[q].y * as.y + acc[q].z * as.z + acc[q].w * as.w;
    float d_ = acc[q].x * ad.x + acc[q].y * ad.y + acc[q].z * ad.z + acc[q].w * ad.w;
    #pragma unroll
    for (int off = 1; off < 16; off <<= 1) {
      s_ += __shfl_xor(s_, off, 64);
      d_ += __shfl_xor(d_, off, 64);
    }
    if (fg == 0) {
      int r = rg * 4 + q;
      src[h * N + i0 + r] = s_;
      dst[h * N + i0 + r] = d_;
    }
  }

  __syncthreads();
  #pragma unroll
  for (int q = 0; q < 4; ++q) {
    *(float4*)&xls[(rg * 4 + q) * 68 + fg * 4] = acc[q];
  }
  __syncthreads();

  {
    const int lane = t & 63;
    const int g    = t >> 6;
    const int q    = lane >> 4;
    const int m    = lane & 15;
    short8* xb8 = (short8*)xtB;
    #pragma unroll
    for (int jcl = 0; jcl < 2; ++jcl) {
      int jc = (i0 >> 5) + jcl;
      short8 bv;
      #pragma unroll
      for (int r = 0; r < 8; ++r) {
        bv[r] = (short)f2bf(xls[(jcl * 32 + q * 8 + r) * 68 + g * 16 + m]);
      }
      xb8[((size_t)(h * 128 + jc) * 4 + g) * 64 + lane] = bv;
    }
  }
}

// ---------------------------------------------------------------------------
// Kernel 2: fused flash PV. grid (128, JSPLIT=8), block 256 (wave = head).
// Ping-pong unroll-2 pipeline: two register sets, NO copies -> the vmcnt
// wait for set-0's loads lands a full chunk later. No launch-bounds clamp
// (R5's spill trap). Row sums via ones-B MFMA. Plain stores, no atomics.
// ---------------------------------------------------------------------------
__global__ __launch_bounds__(256) void k_flash(const int* __restrict__ adj,
                                               const float* __restrict__ src,
                                               const float* __restrict__ dst,
                                               const short* __restrict__ xtB,
                                               float* __restrict__ accP,
                                               float* __restrict__ lP) {
  __shared__ __align__(16) float dls[HEADS][JLEN + 4];
  const int t    = threadIdx.x;
  const int lane = t & 63;
  const int h    = t >> 6;
  const int i0   = blockIdx.x * 32;
  const int js   = blockIdx.y;
  const int q    = lane >> 4;
  const int m    = lane & 15;
  const int koff = q * 8;
  const int jbase = js * JLEN;

  #pragma unroll
  for (int s = 0; s < 2; ++s) {
    int idx = t + 256 * s;            // 0..511
    int hh = idx >> 7, j4 = idx & 127;
    *(float4*)&dls[hh][j4 * 4] = *(const float4*)(dst + (size_t)hh * N + jbase + j4 * 4);
  }

  float sv = (lane < 32) ? src[h * N + i0 + lane] : 0.f;
  const float s0 = __shfl(sv, m, 64);
  const float s1 = __shfl(sv, 16 + m, 64);
  __syncthreads();

  f32x4 acc0[4], acc1[4], accL0, accL1;
  #pragma unroll
  for (int g = 0; g < 4; ++g) { acc0[g] = (f32x4)(0.f); acc1[g] = (f32x4)(0.f); }
  accL0 = (f32x4)(0.f);
  accL1 = (f32x4)(0.f);

  short8 ones;
  #pragma unroll
  for (int r = 0; r < 8; ++r) ones[r] = (short)0x3F80;

  const int* arow0 = adj + (size_t)(i0 + m) * N + jbase + koff;
  const int* arow1 = adj + (size_t)(i0 + 16 + m) * N + jbase + koff;
  const short8* xbb = (const short8*)xtB + ((size_t)(h * 128 + js * NC) * 4) * 64 + lane;

#define LOADA(DA, CIDX) do {                                               \
    const int* r0_ = arow0 + (CIDX) * 32;                                  \
    const int* r1_ = arow1 + (CIDX) * 32;                                  \
    DA[0] = *(const int4*)r0_;  DA[1] = *(const int4*)(r0_ + 4);           \
    DA[2] = *(const int4*)r1_;  DA[3] = *(const int4*)(r1_ + 4);           \
  } while (0)
#define LOADB(DB, CIDX) do {                                               \
    const short8* bb_ = xbb + (size_t)(CIDX) * 256;                        \
    DB[0] = bb_[0]; DB[1] = bb_[64]; DB[2] = bb_[128]; DB[3] = bb_[192];   \
  } while (0)

#define COMPUTE(CA, CB, C) do {                                            \
    const float* dp_ = &dls[h][(C) * 32 + koff];                           \
    union { float4 v[2]; float f[8]; } du;                                 \
    du.v[0] = *(const float4*)dp_;                                         \
    du.v[1] = *(const float4*)(dp_ + 4);                                   \
    const int* a0i = (const int*)&CA[0];                                   \
    const int* a1i = (const int*)&CA[2];                                   \
    int av0[4], av1[4];                                                    \
    _Pragma("unroll")                                                      \
    for (int r2 = 0; r2 < 4; ++r2) {                                       \
      float e, el, p0a, p0b, p1a, p1b;                                     \
      e = s0 + du.f[2 * r2];     el = fmaxf(e, NEG * e);                   \
      el = (a0i[2 * r2] > 0) ? el : -1e30f;      p0a = exp2_fast(el);      \
      e = s0 + du.f[2 * r2 + 1]; el = fmaxf(e, NEG * e);                   \
      el = (a0i[2 * r2 + 1] > 0) ? el : -1e30f;  p0b = exp2_fast(el);      \
      e = s1 + du.f[2 * r2];     el = fmaxf(e, NEG * e);                   \
      el = (a1i[2 * r2] > 0) ? el : -1e30f;      p1a = exp2_fast(el);      \
      e = s1 + du.f[2 * r2 + 1]; el = fmaxf(e, NEG * e);                   \
      el = (a1i[2 * r2 + 1] > 0) ? el : -1e30f;  p1b = exp2_fast(el);      \
      av0[r2] = pack_bf2(p0a, p0b);                                        \
      av1[r2] = pack_bf2(p1a, p1b);                                        \
    }                                                                      \
    short8 af0 = __builtin_bit_cast(short8, *(int4*)av0);                  \
    short8 af1 = __builtin_bit_cast(short8, *(int4*)av1);                  \
    acc0[0] = __builtin_amdgcn_mfma_f32_16x16x32_bf16(af0, CB[0], acc0[0], 0, 0, 0); \
    acc0[1] = __builtin_amdgcn_mfma_f32_16x16x32_bf16(af0, CB[1], acc0[1], 0, 0, 0); \
    acc0[2] = __builtin_amdgcn_mfma_f32_16x16x32_bf16(af0, CB[2], acc0[2], 0, 0, 0); \
    acc0[3] = __builtin_amdgcn_mfma_f32_16x16x32_bf16(af0, CB[3], acc0[3], 0, 0, 0); \
    accL0   = __builtin_amdgcn_mfma_f32_16x16x32_bf16(af0, ones,  accL0,   0, 0, 0); \
    acc1[0] = __builtin_amdgcn_mfma_f32_16x16x32_bf16(af1, CB[0], acc1[0], 0, 0, 0); \
    acc1[1] = __builtin_amdgcn_mfma_f32_16x16x32_bf16(af1, CB[1], acc1[1], 0, 0, 0); \
    acc1[2] = __builtin_amdgcn_mfma_f32_16x16x32_bf16(af1, CB[2], acc1[2], 0, 0, 0); \
    acc1[3] = __builtin_amdgcn_mfma_f32_16x16x32_bf16(af1, CB[3], acc1[3], 0, 0, 0); \
    accL1   = __builtin_amdgcn_mfma_f32_16x16x32_bf16(af1, ones,  accL1,   0, 0, 0); \
  } while (0)

  int4   A0[4], A1[4];
  short8 B0[4], B1[4];
  LOADA(A0, 0); LOADB(B0, 0);
  LOADA(A1, 1); LOADB(B1, 1);

  for (int c = 0; c < NC; c += 2) {
    COMPUTE(A0, B0, c);
    {
      int cn = (c + 2 < NC) ? c + 2 : NC - 1;
      LOADA(A0, cn); LOADB(B0, cn);
    }
    COMPUTE(A1, B1, c + 1);
    {
      int cn = (c + 3 < NC) ? c + 3 : NC - 1;
      LOADA(A1, cn); LOADB(B1, cn);
    }
  }
#undef LOADA
#undef LOADB
#undef COMPUTE

  // ---- epilogue: plain stores into js-partial buffers ----
  float* lp = lP + (size_t)js * (HEADS * N);
  if (m == 0) {
    #pragma unroll
    for (int reg = 0; reg < 4; ++reg) {
      lp[h * N + i0 + q * 4 + reg] = accL0[reg];
      lp[h * N + i0 + 16 + q * 4 + reg] = accL1[reg];
    }
  }

  float* ap = accP + (size_t)js * ((size_t)HEADS * N * OUT_F);
  #pragma unroll
  for (int reg = 0; reg < 4; ++reg) {
    int row0 = i0 + q * 4 + reg;
    int row1 = row0 + 16;
    #pragma unroll
    for (int g = 0; g < 4; ++g) {
      ap[((size_t)h * N + row0) * 64 + g * 16 + m] = acc0[g][reg];
      ap[((size_t)h * N + row1) * 64 + g * 16 + m] = acc1[g][reg];
    }
  }
}

// ---------------------------------------------------------------------------
// Kernel 3: out[i][h*64+f] = sum_js accP / sum_js lP
// ---------------------------------------------------------------------------
__global__ __launch_bounds__(256) void k_div(const float* __restrict__ accP,
                                             const float* __restrict__ lP,
                                             float* __restrict__ out) {
  int v = blockIdx.x * 256 + threadIdx.x;
  int col4 = v & 63;
  int i    = v >> 6;
  int h    = col4 >> 4;
  int fg   = col4 & 15;
  float4 s = make_float4(0.f, 0.f, 0.f, 0.f);
  float ls = 0.f;
  #pragma unroll
  for (int js = 0; js < JSPLIT; ++js) {
    const float4* a4p = (const float4*)(accP + (size_t)js * ((size_t)HEADS * N * OUT_F));
    float4 av = a4p[((size_t)h * N + i) * 16 + fg];
    s.x += av.x; s.y += av.y; s.z += av.z; s.w += av.w;
    ls += lP[(size_t)js * (HEADS * N) + h * N + i];
  }
  float il = 1.f / ls;
  ((float4*)out)[v] = make_float4(s.x * il, s.y * il, s.z * il, s.w * il);
}

extern "C" void kernel_launch(void* const* d_in, const int* in_sizes, int n_in,
                              void* d_out, int out_size, void* d_ws, size_t ws_size,
                              hipStream_t stream) {
  const float* x   = (const float*)d_in[0];
  const float* W   = (const float*)d_in[1];
  const float* a   = (const float*)d_in[2];
  const int*   adj = (const int*)d_in[3];
  float* out = (float*)d_out;

  float* ws   = (float*)d_ws;
  short* xtB  = (short*)ws;                                 // 2 MB
  float* src  = ws + 524288;                                // H*N
  float* dst  = src + HEADS * N;                            // H*N
  float* accP = dst + HEADS * N;                            // JSPLIT*H*N*64 = 33.5 MB
  float* lP   = accP + (size_t)JSPLIT * HEADS * N * OUT_F;  // JSPLIT*H*N

  k_xt<<<dim3(64, 4), 256, 0, stream>>>(x, W, a, xtB, src, dst);
  k_flash<<<dim3(N / 32, JSPLIT), 256, 0, stream>>>(adj, src, dst, xtB, accP, lP);
  k_div<<<dim3((N * OUT_F) / 256), 256, 0, stream>>>(accP, lP, out);
}

// Round 8
// 178.374 us; speedup vs baseline: 1.0828x; 1.0828x over previous
//
#include <hip/hip_runtime.h>
#include <math.h>

#define N 4096
#define IN_F 256
#define OUT_F 64
#define HEADS 4
#define NEG 0.2f
#define JSPLIT 8
#define JLEN (N / JSPLIT)        // 512
#define NC (JLEN / 32)           // 16 chunks
#define LOG2E 1.44269504088896f

typedef float f32x4 __attribute__((ext_vector_type(4)));
typedef short short8 __attribute__((ext_vector_type(8)));

#define FMA4S(A, s, V) do { (A).x = fmaf((s),(V).x,(A).x); (A).y = fmaf((s),(V).y,(A).y); \
                            (A).z = fmaf((s),(V).z,(A).z); (A).w = fmaf((s),(V).w,(A).w); } while(0)

// zero P unless bit R of MS is set: AND float bits with sign-extended bit (bfe+and)
#define MSEL(P, MS, R) (P) = __uint_as_float(__float_as_uint(P) & \
                         (unsigned)(((int)((MS) << (31 - (R)))) >> 31))

__device__ __forceinline__ unsigned short f2bf(float x) {
  unsigned int u = __float_as_uint(x);
  u += 0x7fffu + ((u >> 16) & 1u);   // RNE
  return (unsigned short)(u >> 16);
}

__device__ __forceinline__ float exp2_fast(float x) {
#if __has_builtin(__builtin_amdgcn_exp2f)
  return __builtin_amdgcn_exp2f(x);
#else
  return exp2f(x);
#endif
}

// pack bf16(p1)<<16 | bf16(p0), round-half-up
__device__ __forceinline__ int pack_bf2(float p0, float p1) {
  unsigned u0 = __float_as_uint(p0) + 0x8000u;
  unsigned u1 = __float_as_uint(p1) + 0x8000u;
  return (int)__builtin_amdgcn_perm(u1, u0, 0x07060302u);
}

// ---------------------------------------------------------------------------
// Kernel 1: xt = x @ W[h], 64-row tile, grid (64,4), block 256 (R6-proven).
// Emits src/dst (log2e-scaled) + xtB (bf16 B-frag layout). Appended: adj ->
// bitmask conversion (each block converts a disjoint 16-row strip via ballot).
// ---------------------------------------------------------------------------
__global__ __launch_bounds__(256) void k_xt(const float* __restrict__ x,
                                            const float* __restrict__ W,
                                            const float* __restrict__ a,
                                            const int* __restrict__ adj,
                                            short* __restrict__ xtB,
                                            float* __restrict__ src,
                                            float* __restrict__ dst,
                                            unsigned* __restrict__ mb) {
  __shared__ __align__(16) float xls[64 * 68];
  __shared__ __align__(16) float wls[64 * 64];
  const int t  = threadIdx.x;
  const int h  = blockIdx.y;
  const int i0 = blockIdx.x * 64;
  const int fg = t & 15;
  const int rg = t >> 4;

  float4 acc[4];
  acc[0] = acc[1] = acc[2] = acc[3] = make_float4(0.f, 0.f, 0.f, 0.f);

  const float4* xg = (const float4*)x;
  const float4* wg = (const float4*)W;
  float4* xls4 = (float4*)xls;
  float4* wls4 = (float4*)wls;
  const float4* xr4 = (const float4*)xls;
  const float4* wr4 = (const float4*)wls;

  for (int kt = 0; kt < 4; ++kt) {
    __syncthreads();
    #pragma unroll
    for (int s = 0; s < 4; ++s) {
      int f4i = t + 256 * s;
      int row = f4i >> 4, c4 = f4i & 15;
      xls4[row * 17 + c4] = xg[(size_t)(i0 + row) * 64 + kt * 16 + c4];
    }
    #pragma unroll
    for (int s = 0; s < 4; ++s) {
      int f4i = t + 256 * s;
      int kk = f4i >> 4, c4 = f4i & 15;
      wls4[kk * 16 + c4] = wg[(size_t)(h * 256 + kt * 64 + kk) * 16 + c4];
    }
    __syncthreads();
    #pragma unroll 4
    for (int kk = 0; kk < 64; kk += 4) {
      float4 wv0 = wr4[(kk + 0) * 16 + fg];
      float4 wv1 = wr4[(kk + 1) * 16 + fg];
      float4 wv2 = wr4[(kk + 2) * 16 + fg];
      float4 wv3 = wr4[(kk + 3) * 16 + fg];
      #pragma unroll
      for (int q = 0; q < 4; ++q) {
        float4 xv = xr4[(rg * 4 + q) * 17 + (kk >> 2)];
        FMA4S(acc[q], xv.x, wv0);
        FMA4S(acc[q], xv.y, wv1);
        FMA4S(acc[q], xv.z, wv2);
        FMA4S(acc[q], xv.w, wv3);
      }
    }
  }

  const float4* a4 = (const float4*)a;
  float4 as = a4[h * 32 + fg];
  float4 ad = a4[h * 32 + 16 + fg];
  as.x *= LOG2E; as.y *= LOG2E; as.z *= LOG2E; as.w *= LOG2E;
  ad.x *= LOG2E; ad.y *= LOG2E; ad.z *= LOG2E; ad.w *= LOG2E;
  #pragma unroll
  for (int q = 0; q < 4; ++q) {
    float s_ = acc[q].x * as.x + acc[q].y * as.y + acc[q].z * as.z + acc[q].w * as.w;
    float d_ = acc[q].x * ad.x + acc[q].y * ad.y + acc[q].z * ad.z + acc[q].w * ad.w;
    #pragma unroll
    for (int off = 1; off < 16; off <<= 1) {
      s_ += __shfl_xor(s_, off, 64);
      d_ += __shfl_xor(d_, off, 64);
    }
    if (fg == 0) {
      int r = rg * 4 + q;
      src[h * N + i0 + r] = s_;
      dst[h * N + i0 + r] = d_;
    }
  }

  __syncthreads();
  #pragma unroll
  for (int q = 0; q < 4; ++q) {
    *(float4*)&xls[(rg * 4 + q) * 68 + fg * 4] = acc[q];
  }
  __syncthreads();

  {
    const int lane = t & 63;
    const int g    = t >> 6;
    const int q    = lane >> 4;
    const int m    = lane & 15;
    short8* xb8 = (short8*)xtB;
    #pragma unroll
    for (int jcl = 0; jcl < 2; ++jcl) {
      int jc = (i0 >> 5) + jcl;
      short8 bv;
      #pragma unroll
      for (int r = 0; r < 8; ++r) {
        bv[r] = (short)f2bf(xls[(jcl * 32 + q * 8 + r) * 68 + g * 16 + m]);
      }
      xb8[((size_t)(h * 128 + jc) * 4 + g) * 64 + lane] = bv;
    }
  }

  // ---- adj -> bitmask: this block converts rows [bid*16, bid*16+16) ----
  {
    const int lane = t & 63;
    const int wv   = t >> 6;
    const int bid  = blockIdx.y * 64 + blockIdx.x;   // 0..255
    const int row0 = bid * 16 + wv * 4;
    uint2* mb2 = (uint2*)mb;
    #pragma unroll
    for (int rr = 0; rr < 4; ++rr) {
      int row = row0 + rr;
      const int* ar = adj + (size_t)row * N;
      for (int it = 0; it < 64; it += 4) {
        int a0 = ar[(it + 0) * 64 + lane];
        int a1 = ar[(it + 1) * 64 + lane];
        int a2 = ar[(it + 2) * 64 + lane];
        int a3 = ar[(it + 3) * 64 + lane];
        unsigned long long b0 = __ballot(a0 > 0);
        unsigned long long b1 = __ballot(a1 > 0);
        unsigned long long b2 = __ballot(a2 > 0);
        unsigned long long b3 = __ballot(a3 > 0);
        if (lane == 0) {
          size_t base = (size_t)row * 64 + it;
          mb2[base + 0] = make_uint2((unsigned)b0, (unsigned)(b0 >> 32));
          mb2[base + 1] = make_uint2((unsigned)b1, (unsigned)(b1 >> 32));
          mb2[base + 2] = make_uint2((unsigned)b2, (unsigned)(b2 >> 32));
          mb2[base + 3] = make_uint2((unsigned)b3, (unsigned)(b3 >> 32));
        }
      }
    }
  }
}

// ---------------------------------------------------------------------------
// Kernel 2: fused flash PV. grid (128, JSPLIT=8), block 256 (wave = head).
// R6 copy-prefetch structure; adj via 2 bitmask dwords per chunk (32x less
// traffic, L2-resident). Mask select = bfe+and on fp bits. Row sums via
// ones-B MFMA. Plain stores into js-partial buffers.
// ---------------------------------------------------------------------------
__global__ __launch_bounds__(256) void k_flash(const unsigned* __restrict__ mb,
                                               const float* __restrict__ src,
                                               const float* __restrict__ dst,
                                               const short* __restrict__ xtB,
                                               float* __restrict__ accP,
                                               float* __restrict__ lP) {
  __shared__ __align__(16) float dls[HEADS][JLEN + 4];
  const int t    = threadIdx.x;
  const int lane = t & 63;
  const int h    = t >> 6;
  const int i0   = blockIdx.x * 32;
  const int js   = blockIdx.y;
  const int q    = lane >> 4;
  const int m    = lane & 15;
  const int koff = q * 8;
  const int jbase = js * JLEN;

  #pragma unroll
  for (int s = 0; s < 2; ++s) {
    int idx = t + 256 * s;
    int hh = idx >> 7, j4 = idx & 127;
    *(float4*)&dls[hh][j4 * 4] = *(const float4*)(dst + (size_t)hh * N + jbase + j4 * 4);
  }

  float sv = (lane < 32) ? src[h * N + i0 + lane] : 0.f;
  const float s0 = __shfl(sv, m, 64);
  const float s1 = __shfl(sv, 16 + m, 64);
  __syncthreads();

  f32x4 acc0[4], acc1[4], accL0, accL1;
  #pragma unroll
  for (int g = 0; g < 4; ++g) { acc0[g] = (f32x4)(0.f); acc1[g] = (f32x4)(0.f); }
  accL0 = (f32x4)(0.f);
  accL1 = (f32x4)(0.f);

  short8 ones;
  #pragma unroll
  for (int r = 0; r < 8; ++r) ones[r] = (short)0x3F80;

  const unsigned* mrow0 = mb + (size_t)(i0 + m) * 128 + (jbase >> 5);
  const unsigned* mrow1 = mb + (size_t)(i0 + 16 + m) * 128 + (jbase >> 5);
  const short8* xbb = (const short8*)xtB + ((size_t)(h * 128 + js * NC) * 4) * 64 + lane;

#define LOADC(DM0, DM1, DB, CIDX) do {                                     \
    DM0 = mrow0[CIDX];                                                     \
    DM1 = mrow1[CIDX];                                                     \
    const short8* bb_ = xbb + (size_t)(CIDX) * 256;                        \
    DB[0] = bb_[0]; DB[1] = bb_[64]; DB[2] = bb_[128]; DB[3] = bb_[192];   \
  } while (0)

#define COMPUTE(CM0, CM1, CB, C) do {                                      \
    const float* dp_ = &dls[h][(C) * 32 + koff];                           \
    union { float4 v[2]; float f[8]; } du;                                 \
    du.v[0] = *(const float4*)dp_;                                         \
    du.v[1] = *(const float4*)(dp_ + 4);                                   \
    unsigned ms0 = (CM0) >> koff;                                          \
    unsigned ms1 = (CM1) >> koff;                                          \
    int av0[4], av1[4];                                                    \
    _Pragma("unroll")                                                      \
    for (int r2 = 0; r2 < 4; ++r2) {                                       \
      float e, el, p0a, p0b, p1a, p1b;                                     \
      e = s0 + du.f[2 * r2];     el = fmaxf(e, NEG * e);                   \
      p0a = exp2_fast(el);       MSEL(p0a, ms0, 2 * r2);                   \
      e = s0 + du.f[2 * r2 + 1]; el = fmaxf(e, NEG * e);                   \
      p0b = exp2_fast(el);       MSEL(p0b, ms0, 2 * r2 + 1);               \
      e = s1 + du.f[2 * r2];     el = fmaxf(e, NEG * e);                   \
      p1a = exp2_fast(el);       MSEL(p1a, ms1, 2 * r2);                   \
      e = s1 + du.f[2 * r2 + 1]; el = fmaxf(e, NEG * e);                   \
      p1b = exp2_fast(el);       MSEL(p1b, ms1, 2 * r2 + 1);               \
      av0[r2] = pack_bf2(p0a, p0b);                                        \
      av1[r2] = pack_bf2(p1a, p1b);                                        \
    }                                                                      \
    short8 af0 = __builtin_bit_cast(short8, *(int4*)av0);                  \
    short8 af1 = __builtin_bit_cast(short8, *(int4*)av1);                  \
    acc0[0] = __builtin_amdgcn_mfma_f32_16x16x32_bf16(af0, CB[0], acc0[0], 0, 0, 0); \
    acc0[1] = __builtin_amdgcn_mfma_f32_16x16x32_bf16(af0, CB[1], acc0[1], 0, 0, 0); \
    acc0[2] = __builtin_amdgcn_mfma_f32_16x16x32_bf16(af0, CB[2], acc0[2], 0, 0, 0); \
    acc0[3] = __builtin_amdgcn_mfma_f32_16x16x32_bf16(af0, CB[3], acc0[3], 0, 0, 0); \
    accL0   = __builtin_amdgcn_mfma_f32_16x16x32_bf16(af0, ones,  accL0,   0, 0, 0); \
    acc1[0] = __builtin_amdgcn_mfma_f32_16x16x32_bf16(af1, CB[0], acc1[0], 0, 0, 0); \
    acc1[1] = __builtin_amdgcn_mfma_f32_16x16x32_bf16(af1, CB[1], acc1[1], 0, 0, 0); \
    acc1[2] = __builtin_amdgcn_mfma_f32_16x16x32_bf16(af1, CB[2], acc1[2], 0, 0, 0); \
    acc1[3] = __builtin_amdgcn_mfma_f32_16x16x32_bf16(af1, CB[3], acc1[3], 0, 0, 0); \
    accL1   = __builtin_amdgcn_mfma_f32_16x16x32_bf16(af1, ones,  accL1,   0, 0, 0); \
  } while (0)

  unsigned cM0, cM1, nM0, nM1;
  short8 cB[4], nB[4];
  LOADC(cM0, cM1, cB, 0);

  for (int c = 0; c < NC; ++c) {
    const int cn = (c + 1 < NC) ? c + 1 : c;
    LOADC(nM0, nM1, nB, cn);

    COMPUTE(cM0, cM1, cB, c);

    cM0 = nM0; cM1 = nM1;
    #pragma unroll
    for (int z = 0; z < 4; ++z) cB[z] = nB[z];
  }
#undef LOADC
#undef COMPUTE

  // ---- epilogue: plain stores into js-partial buffers ----
  float* lp = lP + (size_t)js * (HEADS * N);
  if (m == 0) {
    #pragma unroll
    for (int reg = 0; reg < 4; ++reg) {
      lp[h * N + i0 + q * 4 + reg] = accL0[reg];
      lp[h * N + i0 + 16 + q * 4 + reg] = accL1[reg];
    }
  }

  float* ap = accP + (size_t)js * ((size_t)HEADS * N * OUT_F);
  #pragma unroll
  for (int reg = 0; reg < 4; ++reg) {
    int row0 = i0 + q * 4 + reg;
    int row1 = row0 + 16;
    #pragma unroll
    for (int g = 0; g < 4; ++g) {
      ap[((size_t)h * N + row0) * 64 + g * 16 + m] = acc0[g][reg];
      ap[((size_t)h * N + row1) * 64 + g * 16 + m] = acc1[g][reg];
    }
  }
}

// ---------------------------------------------------------------------------
// Kernel 3: out[i][h*64+f] = sum_js accP / sum_js lP
// ---------------------------------------------------------------------------
__global__ __launch_bounds__(256) void k_div(const float* __restrict__ accP,
                                             const float* __restrict__ lP,
                                             float* __restrict__ out) {
  int v = blockIdx.x * 256 + threadIdx.x;
  int col4 = v & 63;
  int i    = v >> 6;
  int h    = col4 >> 4;
  int fg   = col4 & 15;
  float4 s = make_float4(0.f, 0.f, 0.f, 0.f);
  float ls = 0.f;
  #pragma unroll
  for (int js = 0; js < JSPLIT; ++js) {
    const float4* a4p = (const float4*)(accP + (size_t)js * ((size_t)HEADS * N * OUT_F));
    float4 av = a4p[((size_t)h * N + i) * 16 + fg];
    s.x += av.x; s.y += av.y; s.z += av.z; s.w += av.w;
    ls += lP[(size_t)js * (HEADS * N) + h * N + i];
  }
  float il = 1.f / ls;
  ((float4*)out)[v] = make_float4(s.x * il, s.y * il, s.z * il, s.w * il);
}

extern "C" void kernel_launch(void* const* d_in, const int* in_sizes, int n_in,
                              void* d_out, int out_size, void* d_ws, size_t ws_size,
                              hipStream_t stream) {
  const float* x   = (const float*)d_in[0];
  const float* W   = (const float*)d_in[1];
  const float* a   = (const float*)d_in[2];
  const int*   adj = (const int*)d_in[3];
  float* out = (float*)d_out;

  float* ws   = (float*)d_ws;
  short* xtB  = (short*)ws;                                 // 2 MB
  float* src  = ws + 524288;                                // H*N
  float* dst  = src + HEADS * N;                            // H*N
  float* accP = dst + HEADS * N;                            // JSPLIT*H*N*64 = 33.5 MB
  float* lP   = accP + (size_t)JSPLIT * HEADS * N * OUT_F;  // JSPLIT*H*N
  unsigned* mb = (unsigned*)(lP + JSPLIT * HEADS * N);      // N*128 u32 = 2 MB

  k_xt<<<dim3(64, 4), 256, 0, stream>>>(x, W, a, adj, xtB, src, dst, mb);
  k_flash<<<dim3(N / 32, JSPLIT), 256, 0, stream>>>(mb, src, dst, xtB, accP, lP);
  k_div<<<dim3((N * OUT_F) / 256), 256, 0, stream>>>(accP, lP, out);
}

// Round 9
// 147.638 us; speedup vs baseline: 1.3082x; 1.2082x over previous
//
#include <hip/hip_runtime.h>
#include <math.h>

#define N 4096
#define IN_F 256
#define OUT_F 64
#define HEADS 4
#define NEG 0.2f
#define JSPLIT 8
#define JLEN (N / JSPLIT)        // 512
#define NC (JLEN / 32)           // 16 chunks
#define LOG2E 1.44269504088896f

typedef float f32x4 __attribute__((ext_vector_type(4)));
typedef short short8 __attribute__((ext_vector_type(8)));

#define FMA4S(A, s, V) do { (A).x = fmaf((s),(V).x,(A).x); (A).y = fmaf((s),(V).y,(A).y); \
                            (A).z = fmaf((s),(V).z,(A).z); (A).w = fmaf((s),(V).w,(A).w); } while(0)

// zero P unless bit R of MS is set: AND float bits with sign-extended bit
#define MSEL(P, MS, R) (P) = __uint_as_float(__float_as_uint(P) & \
                         (unsigned)(((int)((MS) << (31 - (R)))) >> 31))

__device__ __forceinline__ unsigned short f2bf(float x) {
  unsigned int u = __float_as_uint(x);
  u += 0x7fffu + ((u >> 16) & 1u);   // RNE
  return (unsigned short)(u >> 16);
}

__device__ __forceinline__ float exp2_fast(float x) {
#if __has_builtin(__builtin_amdgcn_exp2f)
  return __builtin_amdgcn_exp2f(x);
#else
  return exp2f(x);
#endif
}

// pack bf16(p1)<<16 | bf16(p0), round-half-up
__device__ __forceinline__ int pack_bf2(float p0, float p1) {
  unsigned u0 = __float_as_uint(p0) + 0x8000u;
  unsigned u1 = __float_as_uint(p1) + 0x8000u;
  return (int)__builtin_amdgcn_perm(u1, u0, 0x07060302u);
}

// ---------------------------------------------------------------------------
// Kernel 0: adj -> bitmask, ballot-free. Thread tid packs adj[tid*8..tid*8+8)
// into one byte. Wave: 2 KB contiguous reads, 64 B contiguous byte stores.
// grid 8192 x 256. Pure HBM stream (67 MB read, 2 MB write).
// ---------------------------------------------------------------------------
__global__ __launch_bounds__(256) void k_mask(const int* __restrict__ adj,
                                              unsigned char* __restrict__ mbB) {
  int tid = blockIdx.x * 256 + threadIdx.x;       // 0 .. N*N/8-1
  const int4* a4 = (const int4*)adj + (size_t)tid * 2;
  int4 v0 = a4[0];
  int4 v1 = a4[1];
  unsigned b = 0;
  b |= (v0.x > 0) ? 0x01u : 0u;
  b |= (v0.y > 0) ? 0x02u : 0u;
  b |= (v0.z > 0) ? 0x04u : 0u;
  b |= (v0.w > 0) ? 0x08u : 0u;
  b |= (v1.x > 0) ? 0x10u : 0u;
  b |= (v1.y > 0) ? 0x20u : 0u;
  b |= (v1.z > 0) ? 0x40u : 0u;
  b |= (v1.w > 0) ? 0x80u : 0u;
  mbB[tid] = (unsigned char)b;
}

// ---------------------------------------------------------------------------
// Kernel 1: xt = x @ W[h], 32-row tile, grid (128,4) = 512 blocks (2/CU).
// LDS-staged x tile + W k-slices. Each thread: 2 rows x 4 cols. Emits
// src/dst (log2e-scaled) + xtB (bf16 B-frag layout; one jc chunk per block).
// ---------------------------------------------------------------------------
__global__ __launch_bounds__(256) void k_xt(const float* __restrict__ x,
                                            const float* __restrict__ W,
                                            const float* __restrict__ a,
                                            short* __restrict__ xtB,
                                            float* __restrict__ src,
                                            float* __restrict__ dst) {
  __shared__ __align__(16) float xls[32 * 68];  // x tile, stride 68 floats
  __shared__ __align__(16) float wls[64 * 64];  // W k-slice
  const int t  = threadIdx.x;
  const int h  = blockIdx.y;
  const int bx = blockIdx.x;
  const int i0 = bx * 32;
  const int fg = t & 15;
  const int rg = t >> 4;

  float4 acc[2];
  acc[0] = acc[1] = make_float4(0.f, 0.f, 0.f, 0.f);

  const float4* xg = (const float4*)x;
  const float4* wg = (const float4*)W;
  float4* xls4 = (float4*)xls;
  float4* wls4 = (float4*)wls;
  const float4* xr4 = (const float4*)xls;
  const float4* wr4 = (const float4*)wls;

  for (int kt = 0; kt < 4; ++kt) {
    __syncthreads();
    // stage x slice: 32 rows x 16 f4 (cols kt*64..)
    #pragma unroll
    for (int s = 0; s < 2; ++s) {
      int f4i = t + 256 * s;              // 0..511
      int row = f4i >> 4, c4 = f4i & 15;
      xls4[row * 17 + c4] = xg[(size_t)(i0 + row) * 64 + kt * 16 + c4];
    }
    // stage W slice: 64 k x 16 f4
    #pragma unroll
    for (int s = 0; s < 4; ++s) {
      int f4i = t + 256 * s;
      int kk = f4i >> 4, c4 = f4i & 15;
      wls4[kk * 16 + c4] = wg[(size_t)(h * 256 + kt * 64 + kk) * 16 + c4];
    }
    __syncthreads();
    #pragma unroll 4
    for (int kk = 0; kk < 64; kk += 4) {
      float4 wv0 = wr4[(kk + 0) * 16 + fg];
      float4 wv1 = wr4[(kk + 1) * 16 + fg];
      float4 wv2 = wr4[(kk + 2) * 16 + fg];
      float4 wv3 = wr4[(kk + 3) * 16 + fg];
      #pragma unroll
      for (int q = 0; q < 2; ++q) {
        float4 xv = xr4[(rg * 2 + q) * 17 + (kk >> 2)];
        FMA4S(acc[q], xv.x, wv0);
        FMA4S(acc[q], xv.y, wv1);
        FMA4S(acc[q], xv.z, wv2);
        FMA4S(acc[q], xv.w, wv3);
      }
    }
  }

  const float4* a4 = (const float4*)a;
  float4 as = a4[h * 32 + fg];
  float4 ad = a4[h * 32 + 16 + fg];
  as.x *= LOG2E; as.y *= LOG2E; as.z *= LOG2E; as.w *= LOG2E;
  ad.x *= LOG2E; ad.y *= LOG2E; ad.z *= LOG2E; ad.w *= LOG2E;
  #pragma unroll
  for (int q = 0; q < 2; ++q) {
    float s_ = acc[q].x * as.x + acc[q].y * as.y + acc[q].z * as.z + acc[q].w * as.w;
    float d_ = acc[q].x * ad.x + acc[q].y * ad.y + acc[q].z * ad.z + acc[q].w * ad.w;
    #pragma unroll
    for (int off = 1; off < 16; off <<= 1) {
      s_ += __shfl_xor(s_, off, 64);
      d_ += __shfl_xor(d_, off, 64);
    }
    if (fg == 0) {
      int r = rg * 2 + q;
      src[h * N + i0 + r] = s_;
      dst[h * N + i0 + r] = d_;
    }
  }

  // restage acc (stride 68) for the B-fragment pack
  __syncthreads();
  #pragma unroll
  for (int q = 0; q < 2; ++q) {
    *(float4*)&xls[(rg * 2 + q) * 68 + fg * 4] = acc[q];
  }
  __syncthreads();

  {
    const int lane = t & 63;
    const int g    = t >> 6;        // col-group 0..3
    const int q    = lane >> 4;     // k-quad
    const int m    = lane & 15;     // B col within group
    short8 bv;
    #pragma unroll
    for (int r = 0; r < 8; ++r) {
      bv[r] = (short)f2bf(xls[(q * 8 + r) * 68 + g * 16 + m]);
    }
    ((short8*)xtB)[((size_t)(h * 128 + bx) * 4 + g) * 64 + lane] = bv;
  }
}

// ---------------------------------------------------------------------------
// Kernel 2: fused flash PV. grid (128, JSPLIT=8), block 256 (wave = head).
// R6 copy-prefetch structure; adj via 2 bitmask dwords per chunk. Row sums
// via ones-B MFMA. Plain stores into js-partial buffers.
// ---------------------------------------------------------------------------
__global__ __launch_bounds__(256) void k_flash(const unsigned* __restrict__ mb,
                                               const float* __restrict__ src,
                                               const float* __restrict__ dst,
                                               const short* __restrict__ xtB,
                                               float* __restrict__ accP,
                                               float* __restrict__ lP) {
  __shared__ __align__(16) float dls[HEADS][JLEN + 4];
  const int t    = threadIdx.x;
  const int lane = t & 63;
  const int h    = t >> 6;
  const int i0   = blockIdx.x * 32;
  const int js   = blockIdx.y;
  const int q    = lane >> 4;
  const int m    = lane & 15;
  const int koff = q * 8;
  const int jbase = js * JLEN;

  #pragma unroll
  for (int s = 0; s < 2; ++s) {
    int idx = t + 256 * s;
    int hh = idx >> 7, j4 = idx & 127;
    *(float4*)&dls[hh][j4 * 4] = *(const float4*)(dst + (size_t)hh * N + jbase + j4 * 4);
  }

  float sv = (lane < 32) ? src[h * N + i0 + lane] : 0.f;
  const float s0 = __shfl(sv, m, 64);
  const float s1 = __shfl(sv, 16 + m, 64);
  __syncthreads();

  f32x4 acc0[4], acc1[4], accL0, accL1;
  #pragma unroll
  for (int g = 0; g < 4; ++g) { acc0[g] = (f32x4)(0.f); acc1[g] = (f32x4)(0.f); }
  accL0 = (f32x4)(0.f);
  accL1 = (f32x4)(0.f);

  short8 ones;
  #pragma unroll
  for (int r = 0; r < 8; ++r) ones[r] = (short)0x3F80;

  const unsigned* mrow0 = mb + (size_t)(i0 + m) * 128 + (jbase >> 5);
  const unsigned* mrow1 = mb + (size_t)(i0 + 16 + m) * 128 + (jbase >> 5);
  const short8* xbb = (const short8*)xtB + ((size_t)(h * 128 + js * NC) * 4) * 64 + lane;

#define LOADC(DM0, DM1, DB, CIDX) do {                                     \
    DM0 = mrow0[CIDX];                                                     \
    DM1 = mrow1[CIDX];                                                     \
    const short8* bb_ = xbb + (size_t)(CIDX) * 256;                        \
    DB[0] = bb_[0]; DB[1] = bb_[64]; DB[2] = bb_[128]; DB[3] = bb_[192];   \
  } while (0)

#define COMPUTE(CM0, CM1, CB, C) do {                                      \
    const float* dp_ = &dls[h][(C) * 32 + koff];                           \
    union { float4 v[2]; float f[8]; } du;                                 \
    du.v[0] = *(const float4*)dp_;                                         \
    du.v[1] = *(const float4*)(dp_ + 4);                                   \
    unsigned ms0 = (CM0) >> koff;                                          \
    unsigned ms1 = (CM1) >> koff;                                          \
    int av0[4], av1[4];                                                    \
    _Pragma("unroll")                                                      \
    for (int r2 = 0; r2 < 4; ++r2) {                                       \
      float e, el, p0a, p0b, p1a, p1b;                                     \
      e = s0 + du.f[2 * r2];     el = fmaxf(e, NEG * e);                   \
      p0a = exp2_fast(el);       MSEL(p0a, ms0, 2 * r2);                   \
      e = s0 + du.f[2 * r2 + 1]; el = fmaxf(e, NEG * e);                   \
      p0b = exp2_fast(el);       MSEL(p0b, ms0, 2 * r2 + 1);               \
      e = s1 + du.f[2 * r2];     el = fmaxf(e, NEG * e);                   \
      p1a = exp2_fast(el);       MSEL(p1a, ms1, 2 * r2);                   \
      e = s1 + du.f[2 * r2 + 1]; el = fmaxf(e, NEG * e);                   \
      p1b = exp2_fast(el);       MSEL(p1b, ms1, 2 * r2 + 1);               \
      av0[r2] = pack_bf2(p0a, p0b);                                        \
      av1[r2] = pack_bf2(p1a, p1b);                                        \
    }                                                                      \
    short8 af0 = __builtin_bit_cast(short8, *(int4*)av0);                  \
    short8 af1 = __builtin_bit_cast(short8, *(int4*)av1);                  \
    acc0[0] = __builtin_amdgcn_mfma_f32_16x16x32_bf16(af0, CB[0], acc0[0], 0, 0, 0); \
    acc0[1] = __builtin_amdgcn_mfma_f32_16x16x32_bf16(af0, CB[1], acc0[1], 0, 0, 0); \
    acc0[2] = __builtin_amdgcn_mfma_f32_16x16x32_bf16(af0, CB[2], acc0[2], 0, 0, 0); \
    acc0[3] = __builtin_amdgcn_mfma_f32_16x16x32_bf16(af0, CB[3], acc0[3], 0, 0, 0); \
    accL0   = __builtin_amdgcn_mfma_f32_16x16x32_bf16(af0, ones,  accL0,   0, 0, 0); \
    acc1[0] = __builtin_amdgcn_mfma_f32_16x16x32_bf16(af1, CB[0], acc1[0], 0, 0, 0); \
    acc1[1] = __builtin_amdgcn_mfma_f32_16x16x32_bf16(af1, CB[1], acc1[1], 0, 0, 0); \
    acc1[2] = __builtin_amdgcn_mfma_f32_16x16x32_bf16(af1, CB[2], acc1[2], 0, 0, 0); \
    acc1[3] = __builtin_amdgcn_mfma_f32_16x16x32_bf16(af1, CB[3], acc1[3], 0, 0, 0); \
    accL1   = __builtin_amdgcn_mfma_f32_16x16x32_bf16(af1, ones,  accL1,   0, 0, 0); \
  } while (0)

  unsigned cM0, cM1, nM0, nM1;
  short8 cB[4], nB[4];
  LOADC(cM0, cM1, cB, 0);

  for (int c = 0; c < NC; ++c) {
    const int cn = (c + 1 < NC) ? c + 1 : c;
    LOADC(nM0, nM1, nB, cn);

    COMPUTE(cM0, cM1, cB, c);

    cM0 = nM0; cM1 = nM1;
    #pragma unroll
    for (int z = 0; z < 4; ++z) cB[z] = nB[z];
  }
#undef LOADC
#undef COMPUTE

  float* lp = lP + (size_t)js * (HEADS * N);
  if (m == 0) {
    #pragma unroll
    for (int reg = 0; reg < 4; ++reg) {
      lp[h * N + i0 + q * 4 + reg] = accL0[reg];
      lp[h * N + i0 + 16 + q * 4 + reg] = accL1[reg];
    }
  }

  float* ap = accP + (size_t)js * ((size_t)HEADS * N * OUT_F);
  #pragma unroll
  for (int reg = 0; reg < 4; ++reg) {
    int row0 = i0 + q * 4 + reg;
    int row1 = row0 + 16;
    #pragma unroll
    for (int g = 0; g < 4; ++g) {
      ap[((size_t)h * N + row0) * 64 + g * 16 + m] = acc0[g][reg];
      ap[((size_t)h * N + row1) * 64 + g * 16 + m] = acc1[g][reg];
    }
  }
}

// ---------------------------------------------------------------------------
// Kernel 3: out[i][h*64+f] = sum_js accP / sum_js lP
// ---------------------------------------------------------------------------
__global__ __launch_bounds__(256) void k_div(const float* __restrict__ accP,
                                             const float* __restrict__ lP,
                                             float* __restrict__ out) {
  int v = blockIdx.x * 256 + threadIdx.x;
  int col4 = v & 63;
  int i    = v >> 6;
  int h    = col4 >> 4;
  int fg   = col4 & 15;
  float4 s = make_float4(0.f, 0.f, 0.f, 0.f);
  float ls = 0.f;
  #pragma unroll
  for (int js = 0; js < JSPLIT; ++js) {
    const float4* a4p = (const float4*)(accP + (size_t)js * ((size_t)HEADS * N * OUT_F));
    float4 av = a4p[((size_t)h * N + i) * 16 + fg];
    s.x += av.x; s.y += av.y; s.z += av.z; s.w += av.w;
    ls += lP[(size_t)js * (HEADS * N) + h * N + i];
  }
  float il = 1.f / ls;
  ((float4*)out)[v] = make_float4(s.x * il, s.y * il, s.z * il, s.w * il);
}

extern "C" void kernel_launch(void* const* d_in, const int* in_sizes, int n_in,
                              void* d_out, int out_size, void* d_ws, size_t ws_size,
                              hipStream_t stream) {
  const float* x   = (const float*)d_in[0];
  const float* W   = (const float*)d_in[1];
  const float* a   = (const float*)d_in[2];
  const int*   adj = (const int*)d_in[3];
  float* out = (float*)d_out;

  float* ws   = (float*)d_ws;
  short* xtB  = (short*)ws;                                 // 2 MB
  float* src  = ws + 524288;                                // H*N
  float* dst  = src + HEADS * N;                            // H*N
  float* accP = dst + HEADS * N;                            // JSPLIT*H*N*64 = 33.5 MB
  float* lP   = accP + (size_t)JSPLIT * HEADS * N * OUT_F;  // JSPLIT*H*N
  unsigned* mb = (unsigned*)(lP + JSPLIT * HEADS * N);      // N*128 u32 = 2 MB

  k_mask<<<dim3(N * N / 8 / 256), 256, 0, stream>>>(adj, (unsigned char*)mb);
  k_xt<<<dim3(128, 4), 256, 0, stream>>>(x, W, a, xtB, src, dst);
  k_flash<<<dim3(N / 32, JSPLIT), 256, 0, stream>>>(mb, src, dst, xtB, accP, lP);
  k_div<<<dim3((N * OUT_F) / 256), 256, 0, stream>>>(accP, lP, out);
}

// Round 10
// 142.451 us; speedup vs baseline: 1.3558x; 1.0364x over previous
//
#include <hip/hip_runtime.h>
#include <math.h>

#define N 4096
#define IN_F 256
#define OUT_F 64
#define HEADS 4
#define NEG 0.2f
#define JSPLIT 8
#define JLEN (N / JSPLIT)        // 512
#define NC (JLEN / 32)           // 16 chunks
#define LOG2E 1.44269504088896f

typedef float f32x4 __attribute__((ext_vector_type(4)));
typedef float f32x2 __attribute__((ext_vector_type(2)));
typedef short short8 __attribute__((ext_vector_type(8)));

#define FMA4S(A, s, V) do { (A).x = fmaf((s),(V).x,(A).x); (A).y = fmaf((s),(V).y,(A).y); \
                            (A).z = fmaf((s),(V).z,(A).z); (A).w = fmaf((s),(V).w,(A).w); } while(0)

// zero P unless bit R of MS is set: AND float bits with sign-extended bit
#define MSEL(P, MS, R) (P) = __uint_as_float(__float_as_uint(P) & \
                         (unsigned)(((int)((MS) << (31 - (R)))) >> 31))

__device__ __forceinline__ unsigned short f2bf(float x) {
  unsigned int u = __float_as_uint(x);
  u += 0x7fffu + ((u >> 16) & 1u);   // RNE
  return (unsigned short)(u >> 16);
}

__device__ __forceinline__ float exp2_fast(float x) {
#if __has_builtin(__builtin_amdgcn_exp2f)
  return __builtin_amdgcn_exp2f(x);
#else
  return exp2f(x);
#endif
}

// pack bf16(p1)<<16 | bf16(p0), round-half-up
__device__ __forceinline__ int pack_bf2(float p0, float p1) {
  unsigned u0 = __float_as_uint(p0) + 0x8000u;
  unsigned u1 = __float_as_uint(p1) + 0x8000u;
  return (int)__builtin_amdgcn_perm(u1, u0, 0x07060302u);
}

// ---------------------------------------------------------------------------
// Kernel 1: fused prep. Blocks [0,512): xt = x @ W[h] (32-row tile, LDS-staged,
// R9-proven) -> src/dst (log2e-scaled) + xtB (bf16 B-frag). Blocks [512,8704):
// adj -> bitmask stream (1 byte per 8 ints per thread). The two partitions are
// data-independent; fusing overlaps the HBM mask stream with the GEMM.
// ---------------------------------------------------------------------------
__global__ __launch_bounds__(256) void k_prep(const float* __restrict__ x,
                                              const float* __restrict__ W,
                                              const float* __restrict__ a,
                                              const int* __restrict__ adj,
                                              short* __restrict__ xtB,
                                              float* __restrict__ src,
                                              float* __restrict__ dst,
                                              unsigned char* __restrict__ mbB) {
  __shared__ __align__(16) float xls[32 * 68];  // x tile, stride 68 floats
  __shared__ __align__(16) float wls[64 * 64];  // W k-slice
  const int t = threadIdx.x;

  if (blockIdx.x >= 512) {
    // ---- mask partition ----
    int tid = (blockIdx.x - 512) * 256 + t;     // 0 .. N*N/8-1
    const int4* a4 = (const int4*)adj + (size_t)tid * 2;
    int4 v0 = a4[0];
    int4 v1 = a4[1];
    unsigned b = 0;
    b |= (v0.x > 0) ? 0x01u : 0u;
    b |= (v0.y > 0) ? 0x02u : 0u;
    b |= (v0.z > 0) ? 0x04u : 0u;
    b |= (v0.w > 0) ? 0x08u : 0u;
    b |= (v1.x > 0) ? 0x10u : 0u;
    b |= (v1.y > 0) ? 0x20u : 0u;
    b |= (v1.z > 0) ? 0x40u : 0u;
    b |= (v1.w > 0) ? 0x80u : 0u;
    mbB[tid] = (unsigned char)b;
    return;
  }

  // ---- xt partition ----
  const int h  = blockIdx.x >> 7;
  const int bx = blockIdx.x & 127;
  const int i0 = bx * 32;
  const int fg = t & 15;
  const int rg = t >> 4;

  float4 acc[2];
  acc[0] = acc[1] = make_float4(0.f, 0.f, 0.f, 0.f);

  const float4* xg = (const float4*)x;
  const float4* wg = (const float4*)W;
  float4* xls4 = (float4*)xls;
  float4* wls4 = (float4*)wls;
  const float4* xr4 = (const float4*)xls;
  const float4* wr4 = (const float4*)wls;

  for (int kt = 0; kt < 4; ++kt) {
    __syncthreads();
    #pragma unroll
    for (int s = 0; s < 2; ++s) {
      int f4i = t + 256 * s;
      int row = f4i >> 4, c4 = f4i & 15;
      xls4[row * 17 + c4] = xg[(size_t)(i0 + row) * 64 + kt * 16 + c4];
    }
    #pragma unroll
    for (int s = 0; s < 4; ++s) {
      int f4i = t + 256 * s;
      int kk = f4i >> 4, c4 = f4i & 15;
      wls4[kk * 16 + c4] = wg[(size_t)(h * 256 + kt * 64 + kk) * 16 + c4];
    }
    __syncthreads();
    #pragma unroll 4
    for (int kk = 0; kk < 64; kk += 4) {
      float4 wv0 = wr4[(kk + 0) * 16 + fg];
      float4 wv1 = wr4[(kk + 1) * 16 + fg];
      float4 wv2 = wr4[(kk + 2) * 16 + fg];
      float4 wv3 = wr4[(kk + 3) * 16 + fg];
      #pragma unroll
      for (int q = 0; q < 2; ++q) {
        float4 xv = xr4[(rg * 2 + q) * 17 + (kk >> 2)];
        FMA4S(acc[q], xv.x, wv0);
        FMA4S(acc[q], xv.y, wv1);
        FMA4S(acc[q], xv.z, wv2);
        FMA4S(acc[q], xv.w, wv3);
      }
    }
  }

  const float4* a4 = (const float4*)a;
  float4 as = a4[h * 32 + fg];
  float4 ad = a4[h * 32 + 16 + fg];
  as.x *= LOG2E; as.y *= LOG2E; as.z *= LOG2E; as.w *= LOG2E;
  ad.x *= LOG2E; ad.y *= LOG2E; ad.z *= LOG2E; ad.w *= LOG2E;
  #pragma unroll
  for (int q = 0; q < 2; ++q) {
    float s_ = acc[q].x * as.x + acc[q].y * as.y + acc[q].z * as.z + acc[q].w * as.w;
    float d_ = acc[q].x * ad.x + acc[q].y * ad.y + acc[q].z * ad.z + acc[q].w * ad.w;
    #pragma unroll
    for (int off = 1; off < 16; off <<= 1) {
      s_ += __shfl_xor(s_, off, 64);
      d_ += __shfl_xor(d_, off, 64);
    }
    if (fg == 0) {
      int r = rg * 2 + q;
      src[h * N + i0 + r] = s_;
      dst[h * N + i0 + r] = d_;
    }
  }

  __syncthreads();
  #pragma unroll
  for (int q = 0; q < 2; ++q) {
    *(float4*)&xls[(rg * 2 + q) * 68 + fg * 4] = acc[q];
  }
  __syncthreads();

  {
    const int lane = t & 63;
    const int g    = t >> 6;
    const int q    = lane >> 4;
    const int m    = lane & 15;
    short8 bv;
    #pragma unroll
    for (int r = 0; r < 8; ++r) {
      bv[r] = (short)f2bf(xls[(q * 8 + r) * 68 + g * 16 + m]);
    }
    ((short8*)xtB)[((size_t)(h * 128 + bx) * 4 + g) * 64 + lane] = bv;
  }
}

// ---------------------------------------------------------------------------
// Kernel 2: fused flash PV. grid (128, JSPLIT=8), block 256 (wave = head).
// R6 copy-prefetch structure; bitmask adj; logit math on float2 vectors to
// invite v_pk_{add,mul,max}_f32 codegen. Row sums via ones-B MFMA.
// ---------------------------------------------------------------------------
__global__ __launch_bounds__(256) void k_flash(const unsigned* __restrict__ mb,
                                               const float* __restrict__ src,
                                               const float* __restrict__ dst,
                                               const short* __restrict__ xtB,
                                               float* __restrict__ accP,
                                               float* __restrict__ lP) {
  __shared__ __align__(16) float dls[HEADS][JLEN + 4];
  const int t    = threadIdx.x;
  const int lane = t & 63;
  const int h    = t >> 6;
  const int i0   = blockIdx.x * 32;
  const int js   = blockIdx.y;
  const int q    = lane >> 4;
  const int m    = lane & 15;
  const int koff = q * 8;
  const int jbase = js * JLEN;

  #pragma unroll
  for (int s = 0; s < 2; ++s) {
    int idx = t + 256 * s;
    int hh = idx >> 7, j4 = idx & 127;
    *(float4*)&dls[hh][j4 * 4] = *(const float4*)(dst + (size_t)hh * N + jbase + j4 * 4);
  }

  float sv = (lane < 32) ? src[h * N + i0 + lane] : 0.f;
  const float s0 = __shfl(sv, m, 64);
  const float s1 = __shfl(sv, 16 + m, 64);
  __syncthreads();

  f32x4 acc0[4], acc1[4], accL0, accL1;
  #pragma unroll
  for (int g = 0; g < 4; ++g) { acc0[g] = (f32x4)(0.f); acc1[g] = (f32x4)(0.f); }
  accL0 = (f32x4)(0.f);
  accL1 = (f32x4)(0.f);

  short8 ones;
  #pragma unroll
  for (int r = 0; r < 8; ++r) ones[r] = (short)0x3F80;

  const f32x2 s02 = (f32x2)(s0);
  const f32x2 s12 = (f32x2)(s1);

  const unsigned* mrow0 = mb + (size_t)(i0 + m) * 128 + (jbase >> 5);
  const unsigned* mrow1 = mb + (size_t)(i0 + 16 + m) * 128 + (jbase >> 5);
  const short8* xbb = (const short8*)xtB + ((size_t)(h * 128 + js * NC) * 4) * 64 + lane;

#define LOADC(DM0, DM1, DB, CIDX) do {                                     \
    DM0 = mrow0[CIDX];                                                     \
    DM1 = mrow1[CIDX];                                                     \
    const short8* bb_ = xbb + (size_t)(CIDX) * 256;                        \
    DB[0] = bb_[0]; DB[1] = bb_[64]; DB[2] = bb_[128]; DB[3] = bb_[192];   \
  } while (0)

#define COMPUTE(CM0, CM1, CB, C) do {                                      \
    const float* dp_ = &dls[h][(C) * 32 + koff];                           \
    union { float4 v[2]; f32x2 h2[4]; float f[8]; } du;                    \
    du.v[0] = *(const float4*)dp_;                                         \
    du.v[1] = *(const float4*)(dp_ + 4);                                   \
    unsigned ms0 = (CM0) >> koff;                                          \
    unsigned ms1 = (CM1) >> koff;                                          \
    int av0[4], av1[4];                                                    \
    _Pragma("unroll")                                                      \
    for (int r2 = 0; r2 < 4; ++r2) {                                       \
      f32x2 d2 = du.h2[r2];                                                \
      f32x2 e0 = s02 + d2;                                                 \
      f32x2 el0 = __builtin_elementwise_max(e0, e0 * NEG);                 \
      f32x2 e1 = s12 + d2;                                                 \
      f32x2 el1 = __builtin_elementwise_max(e1, e1 * NEG);                 \
      float p0a = exp2_fast(el0.x), p0b = exp2_fast(el0.y);                \
      float p1a = exp2_fast(el1.x), p1b = exp2_fast(el1.y);                \
      MSEL(p0a, ms0, 2 * r2);  MSEL(p0b, ms0, 2 * r2 + 1);                 \
      MSEL(p1a, ms1, 2 * r2);  MSEL(p1b, ms1, 2 * r2 + 1);                 \
      av0[r2] = pack_bf2(p0a, p0b);                                        \
      av1[r2] = pack_bf2(p1a, p1b);                                        \
    }                                                                      \
    short8 af0 = __builtin_bit_cast(short8, *(int4*)av0);                  \
    short8 af1 = __builtin_bit_cast(short8, *(int4*)av1);                  \
    acc0[0] = __builtin_amdgcn_mfma_f32_16x16x32_bf16(af0, CB[0], acc0[0], 0, 0, 0); \
    acc0[1] = __builtin_amdgcn_mfma_f32_16x16x32_bf16(af0, CB[1], acc0[1], 0, 0, 0); \
    acc0[2] = __builtin_amdgcn_mfma_f32_16x16x32_bf16(af0, CB[2], acc0[2], 0, 0, 0); \
    acc0[3] = __builtin_amdgcn_mfma_f32_16x16x32_bf16(af0, CB[3], acc0[3], 0, 0, 0); \
    accL0   = __builtin_amdgcn_mfma_f32_16x16x32_bf16(af0, ones,  accL0,   0, 0, 0); \
    acc1[0] = __builtin_amdgcn_mfma_f32_16x16x32_bf16(af1, CB[0], acc1[0], 0, 0, 0); \
    acc1[1] = __builtin_amdgcn_mfma_f32_16x16x32_bf16(af1, CB[1], acc1[1], 0, 0, 0); \
    acc1[2] = __builtin_amdgcn_mfma_f32_16x16x32_bf16(af1, CB[2], acc1[2], 0, 0, 0); \
    acc1[3] = __builtin_amdgcn_mfma_f32_16x16x32_bf16(af1, CB[3], acc1[3], 0, 0, 0); \
    accL1   = __builtin_amdgcn_mfma_f32_16x16x32_bf16(af1, ones,  accL1,   0, 0, 0); \
  } while (0)

  unsigned cM0, cM1, nM0, nM1;
  short8 cB[4], nB[4];
  LOADC(cM0, cM1, cB, 0);

  for (int c = 0; c < NC; ++c) {
    const int cn = (c + 1 < NC) ? c + 1 : c;
    LOADC(nM0, nM1, nB, cn);

    COMPUTE(cM0, cM1, cB, c);

    cM0 = nM0; cM1 = nM1;
    #pragma unroll
    for (int z = 0; z < 4; ++z) cB[z] = nB[z];
  }
#undef LOADC
#undef COMPUTE

  float* lp = lP + (size_t)js * (HEADS * N);
  if (m == 0) {
    #pragma unroll
    for (int reg = 0; reg < 4; ++reg) {
      lp[h * N + i0 + q * 4 + reg] = accL0[reg];
      lp[h * N + i0 + 16 + q * 4 + reg] = accL1[reg];
    }
  }

  float* ap = accP + (size_t)js * ((size_t)HEADS * N * OUT_F);
  #pragma unroll
  for (int reg = 0; reg < 4; ++reg) {
    int row0 = i0 + q * 4 + reg;
    int row1 = row0 + 16;
    #pragma unroll
    for (int g = 0; g < 4; ++g) {
      ap[((size_t)h * N + row0) * 64 + g * 16 + m] = acc0[g][reg];
      ap[((size_t)h * N + row1) * 64 + g * 16 + m] = acc1[g][reg];
    }
  }
}

// ---------------------------------------------------------------------------
// Kernel 3: out[i][h*64+f] = sum_js accP / sum_js lP
// ---------------------------------------------------------------------------
__global__ __launch_bounds__(256) void k_div(const float* __restrict__ accP,
                                             const float* __restrict__ lP,
                                             float* __restrict__ out) {
  int v = blockIdx.x * 256 + threadIdx.x;
  int col4 = v & 63;
  int i    = v >> 6;
  int h    = col4 >> 4;
  int fg   = col4 & 15;
  float4 s = make_float4(0.f, 0.f, 0.f, 0.f);
  float ls = 0.f;
  #pragma unroll
  for (int js = 0; js < JSPLIT; ++js) {
    const float4* a4p = (const float4*)(accP + (size_t)js * ((size_t)HEADS * N * OUT_F));
    float4 av = a4p[((size_t)h * N + i) * 16 + fg];
    s.x += av.x; s.y += av.y; s.z += av.z; s.w += av.w;
    ls += lP[(size_t)js * (HEADS * N) + h * N + i];
  }
  float il = 1.f / ls;
  ((float4*)out)[v] = make_float4(s.x * il, s.y * il, s.z * il, s.w * il);
}

extern "C" void kernel_launch(void* const* d_in, const int* in_sizes, int n_in,
                              void* d_out, int out_size, void* d_ws, size_t ws_size,
                              hipStream_t stream) {
  const float* x   = (const float*)d_in[0];
  const float* W   = (const float*)d_in[1];
  const float* a   = (const float*)d_in[2];
  const int*   adj = (const int*)d_in[3];
  float* out = (float*)d_out;

  float* ws   = (float*)d_ws;
  short* xtB  = (short*)ws;                                 // 2 MB
  float* src  = ws + 524288;                                // H*N
  float* dst  = src + HEADS * N;                            // H*N
  float* accP = dst + HEADS * N;                            // JSPLIT*H*N*64 = 33.5 MB
  float* lP   = accP + (size_t)JSPLIT * HEADS * N * OUT_F;  // JSPLIT*H*N
  unsigned* mb = (unsigned*)(lP + JSPLIT * HEADS * N);      // N*128 u32 = 2 MB

  k_prep<<<dim3(512 + N * N / 8 / 256), 256, 0, stream>>>(x, W, a, adj, xtB, src, dst,
                                                          (unsigned char*)mb);
  k_flash<<<dim3(N / 32, JSPLIT), 256, 0, stream>>>(mb, src, dst, xtB, accP, lP);
  k_div<<<dim3((N * OUT_F) / 256), 256, 0, stream>>>(accP, lP, out);
}

// Round 11
// 140.959 us; speedup vs baseline: 1.3702x; 1.0106x over previous
//
#include <hip/hip_runtime.h>
#include <math.h>

#define N 4096
#define IN_F 256
#define OUT_F 64
#define HEADS 4
#define NEG 0.2f
#define JSPLIT 8
#define JLEN (N / JSPLIT)        // 512
#define NC (JLEN / 32)           // 16 chunks
#define LOG2E 1.44269504088896f

typedef float f32x4 __attribute__((ext_vector_type(4)));
typedef float f32x2 __attribute__((ext_vector_type(2)));
typedef short short8 __attribute__((ext_vector_type(8)));

#define FMA4S(A, s, V) do { (A).x = fmaf((s),(V).x,(A).x); (A).y = fmaf((s),(V).y,(A).y); \
                            (A).z = fmaf((s),(V).z,(A).z); (A).w = fmaf((s),(V).w,(A).w); } while(0)

// zero P unless bit R of MS is set: AND float bits with sign-extended bit
#define MSEL(P, MS, R) (P) = __uint_as_float(__float_as_uint(P) & \
                         (unsigned)(((int)((MS) << (31 - (R)))) >> 31))

__device__ __forceinline__ unsigned short f2bf(float x) {
  unsigned int u = __float_as_uint(x);
  u += 0x7fffu + ((u >> 16) & 1u);   // RNE
  return (unsigned short)(u >> 16);
}

__device__ __forceinline__ float exp2_fast(float x) {
#if __has_builtin(__builtin_amdgcn_exp2f)
  return __builtin_amdgcn_exp2f(x);
#else
  return exp2f(x);
#endif
}

// pack bf16(p1)<<16 | bf16(p0), round-half-up
__device__ __forceinline__ int pack_bf2(float p0, float p1) {
  unsigned u0 = __float_as_uint(p0) + 0x8000u;
  unsigned u1 = __float_as_uint(p1) + 0x8000u;
  return (int)__builtin_amdgcn_perm(u1, u0, 0x07060302u);
}

// ---------------------------------------------------------------------------
// Kernel 1: fused prep. Blocks [0,512): xt = x @ W[h] (32-row tile, LDS-staged)
// -> src/dst (log2e-scaled) + xtB (bf16 B-frag). Blocks [512,8704): adj ->
// bitmask stream. Data-independent partitions overlap HBM stream with GEMM.
// ---------------------------------------------------------------------------
__global__ __launch_bounds__(256) void k_prep(const float* __restrict__ x,
                                              const float* __restrict__ W,
                                              const float* __restrict__ a,
                                              const int* __restrict__ adj,
                                              short* __restrict__ xtB,
                                              float* __restrict__ src,
                                              float* __restrict__ dst,
                                              unsigned char* __restrict__ mbB) {
  __shared__ __align__(16) float xls[32 * 68];
  __shared__ __align__(16) float wls[64 * 64];
  const int t = threadIdx.x;

  if (blockIdx.x >= 512) {
    int tid = (blockIdx.x - 512) * 256 + t;
    const int4* a4 = (const int4*)adj + (size_t)tid * 2;
    int4 v0 = a4[0];
    int4 v1 = a4[1];
    unsigned b = 0;
    b |= (v0.x > 0) ? 0x01u : 0u;
    b |= (v0.y > 0) ? 0x02u : 0u;
    b |= (v0.z > 0) ? 0x04u : 0u;
    b |= (v0.w > 0) ? 0x08u : 0u;
    b |= (v1.x > 0) ? 0x10u : 0u;
    b |= (v1.y > 0) ? 0x20u : 0u;
    b |= (v1.z > 0) ? 0x40u : 0u;
    b |= (v1.w > 0) ? 0x80u : 0u;
    mbB[tid] = (unsigned char)b;
    return;
  }

  const int h  = blockIdx.x >> 7;
  const int bx = blockIdx.x & 127;
  const int i0 = bx * 32;
  const int fg = t & 15;
  const int rg = t >> 4;

  float4 acc[2];
  acc[0] = acc[1] = make_float4(0.f, 0.f, 0.f, 0.f);

  const float4* xg = (const float4*)x;
  const float4* wg = (const float4*)W;
  float4* xls4 = (float4*)xls;
  float4* wls4 = (float4*)wls;
  const float4* xr4 = (const float4*)xls;
  const float4* wr4 = (const float4*)wls;

  for (int kt = 0; kt < 4; ++kt) {
    __syncthreads();
    #pragma unroll
    for (int s = 0; s < 2; ++s) {
      int f4i = t + 256 * s;
      int row = f4i >> 4, c4 = f4i & 15;
      xls4[row * 17 + c4] = xg[(size_t)(i0 + row) * 64 + kt * 16 + c4];
    }
    #pragma unroll
    for (int s = 0; s < 4; ++s) {
      int f4i = t + 256 * s;
      int kk = f4i >> 4, c4 = f4i & 15;
      wls4[kk * 16 + c4] = wg[(size_t)(h * 256 + kt * 64 + kk) * 16 + c4];
    }
    __syncthreads();
    #pragma unroll 4
    for (int kk = 0; kk < 64; kk += 4) {
      float4 wv0 = wr4[(kk + 0) * 16 + fg];
      float4 wv1 = wr4[(kk + 1) * 16 + fg];
      float4 wv2 = wr4[(kk + 2) * 16 + fg];
      float4 wv3 = wr4[(kk + 3) * 16 + fg];
      #pragma unroll
      for (int q = 0; q < 2; ++q) {
        float4 xv = xr4[(rg * 2 + q) * 17 + (kk >> 2)];
        FMA4S(acc[q], xv.x, wv0);
        FMA4S(acc[q], xv.y, wv1);
        FMA4S(acc[q], xv.z, wv2);
        FMA4S(acc[q], xv.w, wv3);
      }
    }
  }

  const float4* a4 = (const float4*)a;
  float4 as = a4[h * 32 + fg];
  float4 ad = a4[h * 32 + 16 + fg];
  as.x *= LOG2E; as.y *= LOG2E; as.z *= LOG2E; as.w *= LOG2E;
  ad.x *= LOG2E; ad.y *= LOG2E; ad.z *= LOG2E; ad.w *= LOG2E;
  #pragma unroll
  for (int q = 0; q < 2; ++q) {
    float s_ = acc[q].x * as.x + acc[q].y * as.y + acc[q].z * as.z + acc[q].w * as.w;
    float d_ = acc[q].x * ad.x + acc[q].y * ad.y + acc[q].z * ad.z + acc[q].w * ad.w;
    #pragma unroll
    for (int off = 1; off < 16; off <<= 1) {
      s_ += __shfl_xor(s_, off, 64);
      d_ += __shfl_xor(d_, off, 64);
    }
    if (fg == 0) {
      int r = rg * 2 + q;
      src[h * N + i0 + r] = s_;
      dst[h * N + i0 + r] = d_;
    }
  }

  __syncthreads();
  #pragma unroll
  for (int q = 0; q < 2; ++q) {
    *(float4*)&xls[(rg * 2 + q) * 68 + fg * 4] = acc[q];
  }
  __syncthreads();

  {
    const int lane = t & 63;
    const int g    = t >> 6;
    const int q    = lane >> 4;
    const int m    = lane & 15;
    short8 bv;
    #pragma unroll
    for (int r = 0; r < 8; ++r) {
      bv[r] = (short)f2bf(xls[(q * 8 + r) * 68 + g * 16 + m]);
    }
    ((short8*)xtB)[((size_t)(h * 128 + bx) * 4 + g) * 64 + lane] = bv;
  }
}

// ---------------------------------------------------------------------------
// Kernel 2: fused flash PV. grid (128, JSPLIT=8), block 256 (wave = head).
// R6 copy-prefetch structure; bitmask adj; f32x2 packed logit math. Partial O
// stored as bf16 pairs (uint): lane m writes (g0,g1)->row*32+m, (g2,g3)->
// row*32+16+m. fp32 accumulate, one rounding per partial.
// ---------------------------------------------------------------------------
__global__ __launch_bounds__(256) void k_flash(const unsigned* __restrict__ mb,
                                               const float* __restrict__ src,
                                               const float* __restrict__ dst,
                                               const short* __restrict__ xtB,
                                               unsigned* __restrict__ accPu,
                                               float* __restrict__ lP) {
  __shared__ __align__(16) float dls[HEADS][JLEN + 4];
  const int t    = threadIdx.x;
  const int lane = t & 63;
  const int h    = t >> 6;
  const int i0   = blockIdx.x * 32;
  const int js   = blockIdx.y;
  const int q    = lane >> 4;
  const int m    = lane & 15;
  const int koff = q * 8;
  const int jbase = js * JLEN;

  #pragma unroll
  for (int s = 0; s < 2; ++s) {
    int idx = t + 256 * s;
    int hh = idx >> 7, j4 = idx & 127;
    *(float4*)&dls[hh][j4 * 4] = *(const float4*)(dst + (size_t)hh * N + jbase + j4 * 4);
  }

  float sv = (lane < 32) ? src[h * N + i0 + lane] : 0.f;
  const float s0 = __shfl(sv, m, 64);
  const float s1 = __shfl(sv, 16 + m, 64);
  __syncthreads();

  f32x4 acc0[4], acc1[4], accL0, accL1;
  #pragma unroll
  for (int g = 0; g < 4; ++g) { acc0[g] = (f32x4)(0.f); acc1[g] = (f32x4)(0.f); }
  accL0 = (f32x4)(0.f);
  accL1 = (f32x4)(0.f);

  short8 ones;
  #pragma unroll
  for (int r = 0; r < 8; ++r) ones[r] = (short)0x3F80;

  const f32x2 s02 = (f32x2)(s0);
  const f32x2 s12 = (f32x2)(s1);

  const unsigned* mrow0 = mb + (size_t)(i0 + m) * 128 + (jbase >> 5);
  const unsigned* mrow1 = mb + (size_t)(i0 + 16 + m) * 128 + (jbase >> 5);
  const short8* xbb = (const short8*)xtB + ((size_t)(h * 128 + js * NC) * 4) * 64 + lane;

#define LOADC(DM0, DM1, DB, CIDX) do {                                     \
    DM0 = mrow0[CIDX];                                                     \
    DM1 = mrow1[CIDX];                                                     \
    const short8* bb_ = xbb + (size_t)(CIDX) * 256;                        \
    DB[0] = bb_[0]; DB[1] = bb_[64]; DB[2] = bb_[128]; DB[3] = bb_[192];   \
  } while (0)

#define COMPUTE(CM0, CM1, CB, C) do {                                      \
    const float* dp_ = &dls[h][(C) * 32 + koff];                           \
    union { float4 v[2]; f32x2 h2[4]; float f[8]; } du;                    \
    du.v[0] = *(const float4*)dp_;                                         \
    du.v[1] = *(const float4*)(dp_ + 4);                                   \
    unsigned ms0 = (CM0) >> koff;                                          \
    unsigned ms1 = (CM1) >> koff;                                          \
    int av0[4], av1[4];                                                    \
    _Pragma("unroll")                                                      \
    for (int r2 = 0; r2 < 4; ++r2) {                                       \
      f32x2 d2 = du.h2[r2];                                                \
      f32x2 e0 = s02 + d2;                                                 \
      f32x2 el0 = __builtin_elementwise_max(e0, e0 * NEG);                 \
      f32x2 e1 = s12 + d2;                                                 \
      f32x2 el1 = __builtin_elementwise_max(e1, e1 * NEG);                 \
      float p0a = exp2_fast(el0.x), p0b = exp2_fast(el0.y);                \
      float p1a = exp2_fast(el1.x), p1b = exp2_fast(el1.y);                \
      MSEL(p0a, ms0, 2 * r2);  MSEL(p0b, ms0, 2 * r2 + 1);                 \
      MSEL(p1a, ms1, 2 * r2);  MSEL(p1b, ms1, 2 * r2 + 1);                 \
      av0[r2] = pack_bf2(p0a, p0b);                                        \
      av1[r2] = pack_bf2(p1a, p1b);                                        \
    }                                                                      \
    short8 af0 = __builtin_bit_cast(short8, *(int4*)av0);                  \
    short8 af1 = __builtin_bit_cast(short8, *(int4*)av1);                  \
    acc0[0] = __builtin_amdgcn_mfma_f32_16x16x32_bf16(af0, CB[0], acc0[0], 0, 0, 0); \
    acc0[1] = __builtin_amdgcn_mfma_f32_16x16x32_bf16(af0, CB[1], acc0[1], 0, 0, 0); \
    acc0[2] = __builtin_amdgcn_mfma_f32_16x16x32_bf16(af0, CB[2], acc0[2], 0, 0, 0); \
    acc0[3] = __builtin_amdgcn_mfma_f32_16x16x32_bf16(af0, CB[3], acc0[3], 0, 0, 0); \
    accL0   = __builtin_amdgcn_mfma_f32_16x16x32_bf16(af0, ones,  accL0,   0, 0, 0); \
    acc1[0] = __builtin_amdgcn_mfma_f32_16x16x32_bf16(af1, CB[0], acc1[0], 0, 0, 0); \
    acc1[1] = __builtin_amdgcn_mfma_f32_16x16x32_bf16(af1, CB[1], acc1[1], 0, 0, 0); \
    acc1[2] = __builtin_amdgcn_mfma_f32_16x16x32_bf16(af1, CB[2], acc1[2], 0, 0, 0); \
    acc1[3] = __builtin_amdgcn_mfma_f32_16x16x32_bf16(af1, CB[3], acc1[3], 0, 0, 0); \
    accL1   = __builtin_amdgcn_mfma_f32_16x16x32_bf16(af1, ones,  accL1,   0, 0, 0); \
  } while (0)

  unsigned cM0, cM1, nM0, nM1;
  short8 cB[4], nB[4];
  LOADC(cM0, cM1, cB, 0);

  for (int c = 0; c < NC; ++c) {
    const int cn = (c + 1 < NC) ? c + 1 : c;
    LOADC(nM0, nM1, nB, cn);

    COMPUTE(cM0, cM1, cB, c);

    cM0 = nM0; cM1 = nM1;
    #pragma unroll
    for (int z = 0; z < 4; ++z) cB[z] = nB[z];
  }
#undef LOADC
#undef COMPUTE

  float* lp = lP + (size_t)js * (HEADS * N);
  if (m == 0) {
    #pragma unroll
    for (int reg = 0; reg < 4; ++reg) {
      lp[h * N + i0 + q * 4 + reg] = accL0[reg];
      lp[h * N + i0 + 16 + q * 4 + reg] = accL1[reg];
    }
  }

  // bf16-packed partial O: (g0,g1) -> row*32+m, (g2,g3) -> row*32+16+m
  unsigned* ap = accPu + (size_t)js * ((size_t)HEADS * N * 32);
  #pragma unroll
  for (int reg = 0; reg < 4; ++reg) {
    int row0 = i0 + q * 4 + reg;
    int row1 = row0 + 16;
    ap[((size_t)h * N + row0) * 32 + m]      = (unsigned)pack_bf2(acc0[0][reg], acc0[1][reg]);
    ap[((size_t)h * N + row0) * 32 + 16 + m] = (unsigned)pack_bf2(acc0[2][reg], acc0[3][reg]);
    ap[((size_t)h * N + row1) * 32 + m]      = (unsigned)pack_bf2(acc1[0][reg], acc1[1][reg]);
    ap[((size_t)h * N + row1) * 32 + 16 + m] = (unsigned)pack_bf2(acc1[2][reg], acc1[3][reg]);
  }
}

// ---------------------------------------------------------------------------
// Kernel 3: out[i][h*64+f] = sum_js unpack(accPu) / sum_js lP
// ---------------------------------------------------------------------------
__global__ __launch_bounds__(256) void k_div(const unsigned* __restrict__ accPu,
                                             const float* __restrict__ lP,
                                             float* __restrict__ out) {
  int v = blockIdx.x * 256 + threadIdx.x;   // float4 index over N*256 floats
  int col4 = v & 63;
  int i    = v >> 6;
  int h    = col4 >> 4;
  int fl   = (col4 & 15) * 4;     // f within head: 0,4,...,60
  int g    = fl >> 4;
  int m0   = fl & 15;
  size_t base = ((size_t)h * N + i) * 32 + (size_t)((g >> 1) * 16 + m0);
  const int hi = g & 1;
  float4 s = make_float4(0.f, 0.f, 0.f, 0.f);
  float ls = 0.f;
  #pragma unroll
  for (int js = 0; js < JSPLIT; ++js) {
    const uint4 u = *(const uint4*)(accPu + (size_t)js * ((size_t)HEADS * N * 32) + base);
    s.x += __uint_as_float(hi ? (u.x & 0xffff0000u) : (u.x << 16));
    s.y += __uint_as_float(hi ? (u.y & 0xffff0000u) : (u.y << 16));
    s.z += __uint_as_float(hi ? (u.z & 0xffff0000u) : (u.z << 16));
    s.w += __uint_as_float(hi ? (u.w & 0xffff0000u) : (u.w << 16));
    ls += lP[(size_t)js * (HEADS * N) + h * N + i];
  }
  float il = 1.f / ls;
  ((float4*)out)[v] = make_float4(s.x * il, s.y * il, s.z * il, s.w * il);
}

extern "C" void kernel_launch(void* const* d_in, const int* in_sizes, int n_in,
                              void* d_out, int out_size, void* d_ws, size_t ws_size,
                              hipStream_t stream) {
  const float* x   = (const float*)d_in[0];
  const float* W   = (const float*)d_in[1];
  const float* a   = (const float*)d_in[2];
  const int*   adj = (const int*)d_in[3];
  float* out = (float*)d_out;

  float* ws    = (float*)d_ws;
  short* xtB   = (short*)ws;                                // 2 MB
  float* src   = ws + 524288;                               // H*N
  float* dst   = src + HEADS * N;                           // H*N
  unsigned* accPu = (unsigned*)(dst + HEADS * N);           // JSPLIT*H*N*32 u32 = 16.8 MB
  float* lP    = (float*)(accPu + (size_t)JSPLIT * HEADS * N * 32);  // JSPLIT*H*N
  unsigned* mb = (unsigned*)(lP + JSPLIT * HEADS * N);      // N*128 u32 = 2 MB

  k_prep<<<dim3(512 + N * N / 8 / 256), 256, 0, stream>>>(x, W, a, adj, xtB, src, dst,
                                                          (unsigned char*)mb);
  k_flash<<<dim3(N / 32, JSPLIT), 256, 0, stream>>>(mb, src, dst, xtB, accPu, lP);
  k_div<<<dim3((N * OUT_F) / 256), 256, 0, stream>>>(accPu, lP, out);
}